// Round 17
// baseline (138.489 us; speedup 1.0000x reference)
//
#include <hip/hip_runtime.h>
#include <cstdint>
#include <cstddef>

#define B_SZ 2
#define N_SEQ 32768
#define NB 2048
#define HD 32
#define LQ 16
#define KCNT 17
#define M_ROWS 65536
#define SCALE_F 0.17677669529663687f /* 32^-0.5 */

typedef __attribute__((ext_vector_type(8))) short sv8;
typedef __attribute__((ext_vector_type(4))) short sv4;
typedef __attribute__((ext_vector_type(4))) float f4;

__device__ __forceinline__ short f2bf(float f) {
  unsigned u = __builtin_bit_cast(unsigned, f);
  u = (u + 0x7FFFu + ((u >> 16) & 1u)) >> 16;
  return (short)u;
}
__device__ __forceinline__ float bf2f(short s) {
  unsigned u = ((unsigned)(unsigned short)s) << 16;
  return __builtin_bit_cast(float, u);
}
__device__ __forceinline__ void gload16(const void* g, void* l) {
  __builtin_amdgcn_global_load_lds(
      (const __attribute__((address_space(1))) unsigned int*)g,
      (__attribute__((address_space(3))) unsigned int*)l, 16, 0, 0);
}
__device__ __forceinline__ f4 mfma16(sv8 a, sv8 b, f4 c) {
  return __builtin_amdgcn_mfma_f32_16x16x32_bf16(a, b, c, 0, 0, 0);
}

// weights only: cast Wqkv (49152 f4) + Wproj (16384 f4) to dense bf16
__global__ __launch_bounds__(256) void cast_w(
    const float* __restrict__ wq, const float* __restrict__ wp,
    short* __restrict__ W1, short* __restrict__ WP1) {
  const int i = blockIdx.x * 256 + threadIdx.x;
  const float* src;
  short* dst;
  int off;
  if (i < 49152) { src = wq; dst = W1; off = i; }
  else if (i < 49152 + 16384) { src = wp; dst = WP1; off = i - 49152; }
  else return;
  float4 v = ((const float4*)src)[off];
  sv4 h = {f2bf(v.x), f2bf(v.y), f2bf(v.z), f2bf(v.w)};
  *(sv4*)&dst[(size_t)off * 4] = h;
}

// ---- fused QKV GEMM: A = X fp32 (cast to bf16 IN-KERNEL during staging,
// T14 async-split: issue fp32 loads for chunk s+1 -> compute chunk s ->
// cvt+ds_write_b128). B = W1 bf16 via global_load_lds. 2-buffer, one
// vmcnt(0)+barrier per chunk (only B's 2 loads remain in flight there;
// A latency is covered by REGISTER prefetch across the MFMA block).
// ds_write mapping (row w*32+i*16+(l>>2), col (l&3)*8) is lane-contiguous
// 16 B per issue = conflict-free, layout identical to gload16 staging.
// Bijective XCD-chunked swizzle (FETCH verified minimal).
__global__ __launch_bounds__(256) void gemm_fused_qkv(
    const float* __restrict__ Xf, const short* __restrict__ B1,
    const float* __restrict__ bias, short* __restrict__ Qbf,
    short* __restrict__ Kbf, short* __restrict__ Vbf) {
  __shared__ __align__(16) short Ahs[2][128][32];
  __shared__ __align__(16) short Bhs[2][128][32];
  const int tid = threadIdx.x;
  const int w = tid >> 6, l = tid & 63;
  const int wm = w >> 1, wn = w & 1;
  const int bid = blockIdx.x;
  const int chunkc = (6 * 512) >> 3;
  const int lbid = (bid & 7) * chunkc + (bid >> 3);
  const int nti = lbid % 6, mti = lbid / 6;
  const int m0 = mti * 128, n0 = nti * 128;
  const int lr = l >> 2, lc = (l & 3) * 8;
  const int fr = l & 15, kg = (l >> 4) * 8;
  const int ar = w * 32 + lr, ac = lc;
  f4 acc[4][4] = {};

  // prologue: stage chunk 0
#pragma unroll
  for (int i = 0; i < 2; ++i)
    gload16(B1 + (size_t)(n0 + w * 32 + i * 16 + lr) * 256 + lc,
            (void*)&Bhs[0][w * 32 + i * 16][0]);
#pragma unroll
  for (int i = 0; i < 2; ++i) {
    const float* ap = Xf + (size_t)(m0 + ar + i * 16) * 256 + ac;
    float4 x0 = *(const float4*)ap;
    float4 x1 = *(const float4*)(ap + 4);
    sv8 o;
    o[0] = f2bf(x0.x); o[1] = f2bf(x0.y); o[2] = f2bf(x0.z); o[3] = f2bf(x0.w);
    o[4] = f2bf(x1.x); o[5] = f2bf(x1.y); o[6] = f2bf(x1.z); o[7] = f2bf(x1.w);
    *(sv8*)&Ahs[0][ar + i * 16][ac] = o;
  }
  asm volatile("s_waitcnt vmcnt(0) lgkmcnt(0)" ::: "memory");
  __builtin_amdgcn_s_barrier();

  for (int s = 0; s < 8; ++s) {
    const int cb = s & 1, nbuf = cb ^ 1;
    float4 pa0[2], pa1[2];
    if (s < 7) {
      const int sk = (s + 1) * 32;
#pragma unroll
      for (int i = 0; i < 2; ++i)
        gload16(B1 + (size_t)(n0 + w * 32 + i * 16 + lr) * 256 + sk + lc,
                (void*)&Bhs[nbuf][w * 32 + i * 16][0]);
#pragma unroll
      for (int i = 0; i < 2; ++i) {
        const float* ap = Xf + (size_t)(m0 + ar + i * 16) * 256 + sk + ac;
        pa0[i] = *(const float4*)ap;
        pa1[i] = *(const float4*)(ap + 4);
      }
    }
    sv8 fa[4], fb[4];
#pragma unroll
    for (int t = 0; t < 4; ++t) {
      fa[t] = *(const sv8*)&Ahs[cb][wm * 64 + t * 16 + fr][kg];
      fb[t] = *(const sv8*)&Bhs[cb][wn * 64 + t * 16 + fr][kg];
    }
#pragma unroll
    for (int mt = 0; mt < 4; ++mt)
#pragma unroll
      for (int nt2 = 0; nt2 < 4; ++nt2)
        acc[mt][nt2] = mfma16(fa[mt], fb[nt2], acc[mt][nt2]);
    if (s < 7) {
#pragma unroll
      for (int i = 0; i < 2; ++i) {
        sv8 o;
        o[0] = f2bf(pa0[i].x); o[1] = f2bf(pa0[i].y);
        o[2] = f2bf(pa0[i].z); o[3] = f2bf(pa0[i].w);
        o[4] = f2bf(pa1[i].x); o[5] = f2bf(pa1[i].y);
        o[6] = f2bf(pa1[i].z); o[7] = f2bf(pa1[i].w);
        *(sv8*)&Ahs[nbuf][ar + i * 16][ac] = o;
      }
    }
    // drain: residual B gload_lds (issued ~16 MFMAs ago) + ds ops visible
    asm volatile("s_waitcnt vmcnt(0) lgkmcnt(0)" ::: "memory");
    __builtin_amdgcn_s_barrier();
  }

  short* dst = (nti < 2) ? Qbf : ((nti < 4) ? Kbf : Vbf);
  const int r0 = (l >> 4) * 4;
#pragma unroll
  for (int mt = 0; mt < 4; ++mt)
#pragma unroll
    for (int nt2 = 0; nt2 < 4; ++nt2) {
      const int n = n0 + wn * 64 + nt2 * 16 + fr;
      const float bv = bias[n];
      const int nn = n & 255;
      const size_t mb = (size_t)(m0 + wm * 64 + mt * 16 + r0);
#pragma unroll
      for (int j = 0; j < 4; ++j)
        dst[(mb + j) * 256 + nn] = f2bf(acc[mt][nt2][j] + bv);
    }
}

// ---- proj GEMM: 2-buffer bf16 (round-15 proven structure) ----
__global__ __launch_bounds__(256) void gemm_proj1(
    const short* __restrict__ A1, const short* __restrict__ B1,
    const float* __restrict__ bias, float* __restrict__ C) {
  __shared__ __align__(16) short Ahs[2][128][32];
  __shared__ __align__(16) short Bhs[2][128][32];
  const int tid = threadIdx.x;
  const int w = tid >> 6, l = tid & 63;
  const int wm = w >> 1, wn = w & 1;
  const int bid = blockIdx.x;
  const int chunkc = (2 * 512) >> 3;
  const int lbid = (bid & 7) * chunkc + (bid >> 3);
  const int nti = lbid % 2, mti = lbid / 2;
  const int m0 = mti * 128, n0 = nti * 128;
  const int lr = l >> 2, lc = (l & 3) * 8;
  const int fr = l & 15, kg = (l >> 4) * 8;
  f4 acc[4][4] = {};
#pragma unroll
  for (int i = 0; i < 2; ++i) {
    const int row = w * 32 + i * 16;
    gload16(A1 + (size_t)(m0 + row + lr) * 256 + lc, (void*)&Ahs[0][row][0]);
    gload16(B1 + (size_t)(n0 + row + lr) * 256 + lc, (void*)&Bhs[0][row][0]);
  }
  asm volatile("s_waitcnt vmcnt(0)" ::: "memory");
  __builtin_amdgcn_s_barrier();
  int cur = 0;
  for (int s = 0; s < 8; ++s) {
    if (s < 7) {
      const int sk = (s + 1) * 32;
#pragma unroll
      for (int i = 0; i < 2; ++i) {
        const int row = w * 32 + i * 16;
        gload16(A1 + (size_t)(m0 + row + lr) * 256 + sk + lc,
                (void*)&Ahs[cur ^ 1][row][0]);
        gload16(B1 + (size_t)(n0 + row + lr) * 256 + sk + lc,
                (void*)&Bhs[cur ^ 1][row][0]);
      }
    }
    if (s > 0) {
      if (s < 7) asm volatile("s_waitcnt vmcnt(4)" ::: "memory");
      else asm volatile("s_waitcnt vmcnt(0)" ::: "memory");
      __builtin_amdgcn_s_barrier();
    }
    sv8 fa[4], fb[4];
#pragma unroll
    for (int t = 0; t < 4; ++t) {
      fa[t] = *(const sv8*)&Ahs[cur][wm * 64 + t * 16 + fr][kg];
      fb[t] = *(const sv8*)&Bhs[cur][wn * 64 + t * 16 + fr][kg];
    }
#pragma unroll
    for (int mt = 0; mt < 4; ++mt)
#pragma unroll
      for (int nt2 = 0; nt2 < 4; ++nt2)
        acc[mt][nt2] = mfma16(fa[mt], fb[nt2], acc[mt][nt2]);
    asm volatile("s_waitcnt lgkmcnt(0)" ::: "memory");
    __builtin_amdgcn_s_barrier();
    cur ^= 1;
  }
  const int r0 = (l >> 4) * 4;
#pragma unroll
  for (int mt = 0; mt < 4; ++mt)
#pragma unroll
    for (int nt2 = 0; nt2 < 4; ++nt2) {
      const int n = n0 + wn * 64 + nt2 * 16 + fr;
      const float bv = bias[n];
      const size_t mb = (size_t)(m0 + wm * 64 + mt * 16 + r0);
#pragma unroll
      for (int j = 0; j < 4; ++j) C[(mb + j) * 256 + n] = acc[mt][nt2][j] + bv;
    }
}

// ---- attn_v7b: MFMA attention. LDS diet: V pad rows removed (vb row index
// clamped &15 — reads finite garbage x pa=0 = exact 0), 30.1 KB -> 5 blk/CU.
__global__ __launch_bounds__(256, 5) void attn_v7(
    const short* __restrict__ Qb, const short* __restrict__ Kb,
    const short* __restrict__ Vb, const int* __restrict__ amask,
    const float* __restrict__ efeat, const float* __restrict__ Wgate,
    const float* __restrict__ bgate, short* __restrict__ AO) {
  __shared__ __align__(16) short Kl[16 * 264];
  __shared__ __align__(16) short Vl[16 * 264];
  __shared__ __align__(16) short Ol[16 * 264];
  __shared__ float4 Es[LQ * KCNT];
  __shared__ int Ms[LQ * KCNT];

  const int tid = threadIdx.x, g = blockIdx.x;
  const int b = g >> 11, nb = g & (NB - 1);
  const size_t tok0 = (size_t)(b * N_SEQ + nb * LQ);
  const int w = tid >> 6, l = tid & 63;
  const int ln = l & 15, lg = l >> 4;
  const f4 fzero = {0.f, 0.f, 0.f, 0.f};

  sv8 qf[2];
#pragma unroll
  for (int hh = 0; hh < 2; ++hh) {
    const int h = w * 2 + hh;
    qf[hh] = *(const sv8*)(Qb + (tok0 + ln) * 256 + h * 32 + lg * 8);
  }

#pragma unroll
  for (int i = 0; i < 2; ++i) {
    const int f = tid + i * 256;
    const int t = f >> 5, c8 = (f & 31) * 8;
    *(sv8*)&Kl[t * 264 + c8] = *(const sv8*)(Kb + (tok0 + t) * 256 + c8);
    *(sv8*)&Vl[t * 264 + c8] = *(const sv8*)(Vb + (tok0 + t) * 256 + c8);
  }
  {
    const float4* esrc = (const float4*)(efeat + (size_t)nb * LQ * KCNT * 4);
    const int* msrc = amask + (size_t)nb * LQ * KCNT;
    Es[tid] = esrc[tid];
    Ms[tid] = msrc[tid];
    if (tid < LQ * KCNT - 256) {
      Es[256 + tid] = esrc[256 + tid];
      Ms[256 + tid] = msrc[256 + tid];
    }
  }
  __syncthreads();

  const int q = ln;
#pragma unroll
  for (int hh = 0; hh < 2; ++hh) {
    const int h = w * 2 + hh;
    sv8 ka = *(const sv8*)&Kl[ln * 264 + h * 32 + lg * 8];
    f4 sr = mfma16(ka, qf[hh], fzero);

    const float wg0 = Wgate[h * 4], wg1 = Wgate[h * 4 + 1];
    const float wg2 = Wgate[h * 4 + 2], wg3 = Wgate[h * 4 + 3];
    const float bg = bgate[h];

    float rs = sr[0] + sr[1] + sr[2] + sr[3];
    rs += __shfl_xor(rs, 16);
    rs += __shfl_xor(rs, 32);

    float s_[4], gt_[4];
    int vis_[4];
#pragma unroll
    for (int j = 0; j < 4; ++j) {
      const int kc = lg * 4 + j;
      float e0, e1, e2, e3;
      if (kc == q) { e0 = e1 = e2 = 0.f; e3 = 1.f; }
      else { float4 e = Es[q * KCNT + kc]; e0 = e.x; e1 = e.y; e2 = e.z; e3 = e.w; }
      const int m = Ms[q * KCNT + kc];
      vis_[j] = m;
      s_[j] = sr[j] * SCALE_F + e3;
      gt_[j] = m ? (e0 * wg0 + e1 * wg1 + e2 * wg2 + e3 * wg3 + bg) : 0.f;
    }
    const int m16 = Ms[q * KCNT + 16];
    const float s16 = rs * 0.0625f * SCALE_F + 1.0f;

    float mx = -1e30f;
#pragma unroll
    for (int j = 0; j < 4; ++j)
      if (vis_[j]) mx = fmaxf(mx, s_[j]);
    mx = fmaxf(mx, __shfl_xor(mx, 16));
    mx = fmaxf(mx, __shfl_xor(mx, 32));
    if (m16) mx = fmaxf(mx, s16);

    float p_[4], den = 0.f;
#pragma unroll
    for (int j = 0; j < 4; ++j) {
      p_[j] = vis_[j] ? __expf(s_[j] - mx) : 0.f;
      den += p_[j];
    }
    den += __shfl_xor(den, 16);
    den += __shfl_xor(den, 32);
    const float p16 = m16 ? __expf(s16 - mx) : 0.f;
    den += p16;
    const float inv = 1.f / den;
    const float gt16 = m16 ? (wg3 + bg) : 0.f;
    const float cb16 = (p16 * inv + gt16) * 0.0625f;
    float pc[4];
#pragma unroll
    for (int j = 0; j < 4; ++j) pc[j] = p_[j] * inv + gt_[j] + cb16;

    sv8 pa;
#pragma unroll
    for (int e = 0; e < 8; ++e) {
      const int kc = lg * 8 + e;
      const int src = ((kc >> 2) << 4) | q;
      const float v0 = __shfl(pc[e & 3], src);
      pa[e] = (kc < 16) ? f2bf(v0) : (short)0;
    }

#pragma unroll
    for (int t = 0; t < 2; ++t) {
      sv8 vb;
#pragma unroll
      for (int e = 0; e < 8; ++e) {
        const int vr = (lg * 8 + e) & 15;  // clamp: pa[e]=0 for kc>=16
        vb[e] = Vl[vr * 264 + h * 32 + t * 16 + ln];
      }
      f4 oacc = mfma16(pa, vb, fzero);
#pragma unroll
      for (int j = 0; j < 4; ++j)
        Ol[(lg * 4 + j) * 264 + h * 32 + t * 16 + ln] = f2bf(oacc[j]);
    }
  }
  __syncthreads();

#pragma unroll
  for (int i = 0; i < 2; ++i) {
    const int f = tid + i * 256;
    const int t = f >> 5, c8 = (f & 31) * 8;
    *(sv8*)(AO + (tok0 + t) * 256 + c8) = *(const sv8*)&Ol[t * 264 + c8];
  }
}

extern "C" void kernel_launch(void* const* d_in, const int* in_sizes, int n_in,
                              void* d_out, int out_size, void* d_ws, size_t ws_size,
                              hipStream_t stream) {
  const float* x = (const float*)d_in[0];
  const int* amask = (const int*)d_in[1];
  const float* efeat = (const float*)d_in[2];
  const float* Wqkv = (const float*)d_in[3];
  const float* bqkv = (const float*)d_in[4];
  const float* Wproj = (const float*)d_in[5];
  const float* bproj = (const float*)d_in[6];
  const float* Wgate = (const float*)d_in[7];
  const float* bgate = (const float*)d_in[8];
  float* out = (float*)d_out;

  char* ws = (char*)d_ws;
  const size_t QB_SZ = (size_t)M_ROWS * 256 * 2;  // 32 MiB each
  const size_t W1_SZ = (size_t)768 * 256 * 2;     // 384 KiB
  const size_t WP1_SZ = (size_t)256 * 256 * 2;    // 128 KiB
  if (ws_size < 4 * QB_SZ + W1_SZ + WP1_SZ) return;

  short* Qbf = (short*)ws;
  short* Kbf = (short*)(ws + QB_SZ);
  short* Vbf = (short*)(ws + 2 * QB_SZ);
  short* AOh = (short*)(ws + 3 * QB_SZ);
  short* W1 = (short*)(ws + 4 * QB_SZ);
  short* WP1 = (short*)(ws + 4 * QB_SZ + W1_SZ);

  cast_w<<<dim3((49152 + 16384 + 255) / 256), 256, 0, stream>>>(Wqkv, Wproj,
                                                                W1, WP1);
  gemm_fused_qkv<<<dim3(6 * 512), 256, 0, stream>>>(x, W1, bqkv, Qbf, Kbf, Vbf);
  attn_v7<<<dim3(B_SZ * NB), 256, 0, stream>>>(Qbf, Kbf, Vbf, amask, efeat,
                                               Wgate, bgate, AOh);
  gemm_proj1<<<dim3(2 * 512), 256, 0, stream>>>(AOh, WP1, bproj, out);
}

// Round 18
// 122.844 us; speedup vs baseline: 1.1274x; 1.1274x over previous
//
#include <hip/hip_runtime.h>
#include <cstdint>
#include <cstddef>

#define B_SZ 2
#define N_SEQ 32768
#define NB 2048
#define HD 32
#define LQ 16
#define KCNT 17
#define M_ROWS 65536
#define SCALE_F 0.17677669529663687f /* 32^-0.5 */

typedef __attribute__((ext_vector_type(8))) short sv8;
typedef __attribute__((ext_vector_type(4))) short sv4;
typedef __attribute__((ext_vector_type(4))) float f4;

__device__ __forceinline__ short f2bf(float f) {
  unsigned u = __builtin_bit_cast(unsigned, f);
  u = (u + 0x7FFFu + ((u >> 16) & 1u)) >> 16;
  return (short)u;
}
__device__ __forceinline__ float bf2f(short s) {
  unsigned u = ((unsigned)(unsigned short)s) << 16;
  return __builtin_bit_cast(float, u);
}
__device__ __forceinline__ void gload16(const void* g, void* l) {
  __builtin_amdgcn_global_load_lds(
      (const __attribute__((address_space(1))) unsigned int*)g,
      (__attribute__((address_space(3))) unsigned int*)l, 16, 0, 0);
}
__device__ __forceinline__ f4 mfma16(sv8 a, sv8 b, f4 c) {
  return __builtin_amdgcn_mfma_f32_16x16x32_bf16(a, b, c, 0, 0, 0);
}

// fused prep: cast X (4194304 f4), Wqkv (49152 f4), Wproj (16384 f4) to bf16
__global__ __launch_bounds__(256) void cast_all(
    const float* __restrict__ x, const float* __restrict__ wq,
    const float* __restrict__ wp, short* __restrict__ X1,
    short* __restrict__ W1, short* __restrict__ WP1) {
  const int i = blockIdx.x * 256 + threadIdx.x;
  const float* src;
  short* dst;
  int off;
  if (i < 4194304) { src = x; dst = X1; off = i; }
  else if (i < 4194304 + 49152) { src = wq; dst = W1; off = i - 4194304; }
  else if (i < 4194304 + 49152 + 16384) { src = wp; dst = WP1; off = i - 4194304 - 49152; }
  else return;
  float4 v = ((const float4*)src)[off];
  sv4 h = {f2bf(v.x), f2bf(v.y), f2bf(v.z), f2bf(v.w)};
  *(sv4*)&dst[(size_t)off * 4] = h;
}

// ---- QKV GEMM: round-15 proven 2-buffer counted-vmcnt K-loop + NEW
// LDS-staged coalesced epilogue. The 51-us ceiling diagnosis: bf16 stores in
// 32-B segments were write-granularity-bound. Now: acc -> 32 KB LDS tile
// (reuses the K-loop staging union; n XOR-swizzled by ((m&7)<<3) to cap
// epilogue-LDS-write conflicts at 4-way; read side is a within-row
// permutation = conflict-free) -> sv8 stores, 256 B contiguous per row.
__global__ __launch_bounds__(256) void gemm_bf_qkv(
    const short* __restrict__ A1, const short* __restrict__ B1,
    const float* __restrict__ bias, short* __restrict__ Qbf,
    short* __restrict__ Kbf, short* __restrict__ Vbf) {
  __shared__ __align__(16) short LB[2][2][128][32];  // [buf][A|B][row][col]
  const int tid = threadIdx.x;
  const int w = tid >> 6, l = tid & 63;
  const int wm = w >> 1, wn = w & 1;
  const int bid = blockIdx.x;
  const int chunkc = (6 * 512) >> 3;
  const int lbid = (bid & 7) * chunkc + (bid >> 3);
  const int nti = lbid % 6, mti = lbid / 6;
  const int m0 = mti * 128, n0 = nti * 128;
  const int lr = l >> 2, lc = (l & 3) * 8;
  const int fr = l & 15, kg = (l >> 4) * 8;
  f4 acc[4][4] = {};
#pragma unroll
  for (int i = 0; i < 2; ++i) {
    const int row = w * 32 + i * 16;
    gload16(A1 + (size_t)(m0 + row + lr) * 256 + lc, (void*)&LB[0][0][row][0]);
    gload16(B1 + (size_t)(n0 + row + lr) * 256 + lc, (void*)&LB[0][1][row][0]);
  }
  asm volatile("s_waitcnt vmcnt(0)" ::: "memory");
  __builtin_amdgcn_s_barrier();
  int cur = 0;
  for (int s = 0; s < 8; ++s) {
    if (s < 7) {
      const int sk = (s + 1) * 32;
#pragma unroll
      for (int i = 0; i < 2; ++i) {
        const int row = w * 32 + i * 16;
        gload16(A1 + (size_t)(m0 + row + lr) * 256 + sk + lc,
                (void*)&LB[cur ^ 1][0][row][0]);
        gload16(B1 + (size_t)(n0 + row + lr) * 256 + sk + lc,
                (void*)&LB[cur ^ 1][1][row][0]);
      }
    }
    if (s > 0) {
      if (s < 7) asm volatile("s_waitcnt vmcnt(4)" ::: "memory");
      else asm volatile("s_waitcnt vmcnt(0)" ::: "memory");
      __builtin_amdgcn_s_barrier();
    }
    sv8 fa[4], fb[4];
#pragma unroll
    for (int t = 0; t < 4; ++t) {
      fa[t] = *(const sv8*)&LB[cur][0][wm * 64 + t * 16 + fr][kg];
      fb[t] = *(const sv8*)&LB[cur][1][wn * 64 + t * 16 + fr][kg];
    }
#pragma unroll
    for (int mt = 0; mt < 4; ++mt)
#pragma unroll
      for (int nt2 = 0; nt2 < 4; ++nt2)
        acc[mt][nt2] = mfma16(fa[mt], fb[nt2], acc[mt][nt2]);
    asm volatile("s_waitcnt lgkmcnt(0)" ::: "memory");
    __builtin_amdgcn_s_barrier();
    cur ^= 1;
  }
  // ---- epilogue: acc (+bias, ->bf16) into swizzled LDS tile, then coalesced
  short* Lout = &LB[0][0][0][0];  // 128x128 shorts = 32 KB (whole union)
  const int r0 = (l >> 4) * 4;
#pragma unroll
  for (int mt = 0; mt < 4; ++mt)
#pragma unroll
    for (int nt2 = 0; nt2 < 4; ++nt2) {
      const int n = wn * 64 + nt2 * 16 + fr;
      const float bv = bias[n0 + n];
#pragma unroll
      for (int j = 0; j < 4; ++j) {
        const int m = wm * 64 + mt * 16 + r0 + j;
        Lout[m * 128 + (n ^ ((m & 7) << 3))] = f2bf(acc[mt][nt2][j] + bv);
      }
    }
  __builtin_amdgcn_s_barrier();
  short* dst = (nti < 2) ? Qbf : ((nti < 4) ? Kbf : Vbf);
  const int nnb = (nti & 1) * 128;
  const int rrow = tid >> 4, seg = (tid & 15) * 8;
#pragma unroll
  for (int p = 0; p < 8; ++p) {
    const int row = p * 16 + rrow;
    sv8 v = *(const sv8*)&Lout[row * 128 + (seg ^ ((row & 7) << 3))];
    *(sv8*)&dst[(size_t)(m0 + row) * 256 + nnb + seg] = v;
  }
}

// ---- proj GEMM: 2-buffer bf16 (round-15 proven structure), fp32 out ----
__global__ __launch_bounds__(256) void gemm_proj1(
    const short* __restrict__ A1, const short* __restrict__ B1,
    const float* __restrict__ bias, float* __restrict__ C) {
  __shared__ __align__(16) short Ahs[2][128][32];
  __shared__ __align__(16) short Bhs[2][128][32];
  const int tid = threadIdx.x;
  const int w = tid >> 6, l = tid & 63;
  const int wm = w >> 1, wn = w & 1;
  const int bid = blockIdx.x;
  const int chunkc = (2 * 512) >> 3;
  const int lbid = (bid & 7) * chunkc + (bid >> 3);
  const int nti = lbid % 2, mti = lbid / 2;
  const int m0 = mti * 128, n0 = nti * 128;
  const int lr = l >> 2, lc = (l & 3) * 8;
  const int fr = l & 15, kg = (l >> 4) * 8;
  f4 acc[4][4] = {};
#pragma unroll
  for (int i = 0; i < 2; ++i) {
    const int row = w * 32 + i * 16;
    gload16(A1 + (size_t)(m0 + row + lr) * 256 + lc, (void*)&Ahs[0][row][0]);
    gload16(B1 + (size_t)(n0 + row + lr) * 256 + lc, (void*)&Bhs[0][row][0]);
  }
  asm volatile("s_waitcnt vmcnt(0)" ::: "memory");
  __builtin_amdgcn_s_barrier();
  int cur = 0;
  for (int s = 0; s < 8; ++s) {
    if (s < 7) {
      const int sk = (s + 1) * 32;
#pragma unroll
      for (int i = 0; i < 2; ++i) {
        const int row = w * 32 + i * 16;
        gload16(A1 + (size_t)(m0 + row + lr) * 256 + sk + lc,
                (void*)&Ahs[cur ^ 1][row][0]);
        gload16(B1 + (size_t)(n0 + row + lr) * 256 + sk + lc,
                (void*)&Bhs[cur ^ 1][row][0]);
      }
    }
    if (s > 0) {
      if (s < 7) asm volatile("s_waitcnt vmcnt(4)" ::: "memory");
      else asm volatile("s_waitcnt vmcnt(0)" ::: "memory");
      __builtin_amdgcn_s_barrier();
    }
    sv8 fa[4], fb[4];
#pragma unroll
    for (int t = 0; t < 4; ++t) {
      fa[t] = *(const sv8*)&Ahs[cur][wm * 64 + t * 16 + fr][kg];
      fb[t] = *(const sv8*)&Bhs[cur][wn * 64 + t * 16 + fr][kg];
    }
#pragma unroll
    for (int mt = 0; mt < 4; ++mt)
#pragma unroll
      for (int nt2 = 0; nt2 < 4; ++nt2)
        acc[mt][nt2] = mfma16(fa[mt], fb[nt2], acc[mt][nt2]);
    asm volatile("s_waitcnt lgkmcnt(0)" ::: "memory");
    __builtin_amdgcn_s_barrier();
    cur ^= 1;
  }
  const int r0 = (l >> 4) * 4;
#pragma unroll
  for (int mt = 0; mt < 4; ++mt)
#pragma unroll
    for (int nt2 = 0; nt2 < 4; ++nt2) {
      const int n = n0 + wn * 64 + nt2 * 16 + fr;
      const float bv = bias[n];
      const size_t mb = (size_t)(m0 + wm * 64 + mt * 16 + r0);
#pragma unroll
      for (int j = 0; j < 4; ++j) C[(mb + j) * 256 + n] = acc[mt][nt2][j] + bv;
    }
}

// ---- attn_v7b: MFMA attention, LDS-diet (5 blocks/CU), unchanged ----
__global__ __launch_bounds__(256, 5) void attn_v7(
    const short* __restrict__ Qb, const short* __restrict__ Kb,
    const short* __restrict__ Vb, const int* __restrict__ amask,
    const float* __restrict__ efeat, const float* __restrict__ Wgate,
    const float* __restrict__ bgate, short* __restrict__ AO) {
  __shared__ __align__(16) short Kl[16 * 264];
  __shared__ __align__(16) short Vl[16 * 264];
  __shared__ __align__(16) short Ol[16 * 264];
  __shared__ float4 Es[LQ * KCNT];
  __shared__ int Ms[LQ * KCNT];

  const int tid = threadIdx.x, g = blockIdx.x;
  const int b = g >> 11, nb = g & (NB - 1);
  const size_t tok0 = (size_t)(b * N_SEQ + nb * LQ);
  const int w = tid >> 6, l = tid & 63;
  const int ln = l & 15, lg = l >> 4;
  const f4 fzero = {0.f, 0.f, 0.f, 0.f};

  sv8 qf[2];
#pragma unroll
  for (int hh = 0; hh < 2; ++hh) {
    const int h = w * 2 + hh;
    qf[hh] = *(const sv8*)(Qb + (tok0 + ln) * 256 + h * 32 + lg * 8);
  }

#pragma unroll
  for (int i = 0; i < 2; ++i) {
    const int f = tid + i * 256;
    const int t = f >> 5, c8 = (f & 31) * 8;
    *(sv8*)&Kl[t * 264 + c8] = *(const sv8*)(Kb + (tok0 + t) * 256 + c8);
    *(sv8*)&Vl[t * 264 + c8] = *(const sv8*)(Vb + (tok0 + t) * 256 + c8);
  }
  {
    const float4* esrc = (const float4*)(efeat + (size_t)nb * LQ * KCNT * 4);
    const int* msrc = amask + (size_t)nb * LQ * KCNT;
    Es[tid] = esrc[tid];
    Ms[tid] = msrc[tid];
    if (tid < LQ * KCNT - 256) {
      Es[256 + tid] = esrc[256 + tid];
      Ms[256 + tid] = msrc[256 + tid];
    }
  }
  __syncthreads();

  const int q = ln;
#pragma unroll
  for (int hh = 0; hh < 2; ++hh) {
    const int h = w * 2 + hh;
    sv8 ka = *(const sv8*)&Kl[ln * 264 + h * 32 + lg * 8];
    f4 sr = mfma16(ka, qf[hh], fzero);

    const float wg0 = Wgate[h * 4], wg1 = Wgate[h * 4 + 1];
    const float wg2 = Wgate[h * 4 + 2], wg3 = Wgate[h * 4 + 3];
    const float bg = bgate[h];

    float rs = sr[0] + sr[1] + sr[2] + sr[3];
    rs += __shfl_xor(rs, 16);
    rs += __shfl_xor(rs, 32);

    float s_[4], gt_[4];
    int vis_[4];
#pragma unroll
    for (int j = 0; j < 4; ++j) {
      const int kc = lg * 4 + j;
      float e0, e1, e2, e3;
      if (kc == q) { e0 = e1 = e2 = 0.f; e3 = 1.f; }
      else { float4 e = Es[q * KCNT + kc]; e0 = e.x; e1 = e.y; e2 = e.z; e3 = e.w; }
      const int m = Ms[q * KCNT + kc];
      vis_[j] = m;
      s_[j] = sr[j] * SCALE_F + e3;
      gt_[j] = m ? (e0 * wg0 + e1 * wg1 + e2 * wg2 + e3 * wg3 + bg) : 0.f;
    }
    const int m16 = Ms[q * KCNT + 16];
    const float s16 = rs * 0.0625f * SCALE_F + 1.0f;

    float mx = -1e30f;
#pragma unroll
    for (int j = 0; j < 4; ++j)
      if (vis_[j]) mx = fmaxf(mx, s_[j]);
    mx = fmaxf(mx, __shfl_xor(mx, 16));
    mx = fmaxf(mx, __shfl_xor(mx, 32));
    if (m16) mx = fmaxf(mx, s16);

    float p_[4], den = 0.f;
#pragma unroll
    for (int j = 0; j < 4; ++j) {
      p_[j] = vis_[j] ? __expf(s_[j] - mx) : 0.f;
      den += p_[j];
    }
    den += __shfl_xor(den, 16);
    den += __shfl_xor(den, 32);
    const float p16 = m16 ? __expf(s16 - mx) : 0.f;
    den += p16;
    const float inv = 1.f / den;
    const float gt16 = m16 ? (wg3 + bg) : 0.f;
    const float cb16 = (p16 * inv + gt16) * 0.0625f;
    float pc[4];
#pragma unroll
    for (int j = 0; j < 4; ++j) pc[j] = p_[j] * inv + gt_[j] + cb16;

    sv8 pa;
#pragma unroll
    for (int e = 0; e < 8; ++e) {
      const int kc = lg * 8 + e;
      const int src = ((kc >> 2) << 4) | q;
      const float v0 = __shfl(pc[e & 3], src);
      pa[e] = (kc < 16) ? f2bf(v0) : (short)0;
    }

#pragma unroll
    for (int t = 0; t < 2; ++t) {
      sv8 vb;
#pragma unroll
      for (int e = 0; e < 8; ++e) {
        const int vr = (lg * 8 + e) & 15;  // clamp: pa[e]=0 for kc>=16
        vb[e] = Vl[vr * 264 + h * 32 + t * 16 + ln];
      }
      f4 oacc = mfma16(pa, vb, fzero);
#pragma unroll
      for (int j = 0; j < 4; ++j)
        Ol[(lg * 4 + j) * 264 + h * 32 + t * 16 + ln] = f2bf(oacc[j]);
    }
  }
  __syncthreads();

#pragma unroll
  for (int i = 0; i < 2; ++i) {
    const int f = tid + i * 256;
    const int t = f >> 5, c8 = (f & 31) * 8;
    *(sv8*)(AO + (tok0 + t) * 256 + c8) = *(const sv8*)&Ol[t * 264 + c8];
  }
}

extern "C" void kernel_launch(void* const* d_in, const int* in_sizes, int n_in,
                              void* d_out, int out_size, void* d_ws, size_t ws_size,
                              hipStream_t stream) {
  const float* x = (const float*)d_in[0];
  const int* amask = (const int*)d_in[1];
  const float* efeat = (const float*)d_in[2];
  const float* Wqkv = (const float*)d_in[3];
  const float* bqkv = (const float*)d_in[4];
  const float* Wproj = (const float*)d_in[5];
  const float* bproj = (const float*)d_in[6];
  const float* Wgate = (const float*)d_in[7];
  const float* bgate = (const float*)d_in[8];
  float* out = (float*)d_out;

  char* ws = (char*)d_ws;
  const size_t QB_SZ = (size_t)M_ROWS * 256 * 2;  // 32 MiB each
  const size_t W1_SZ = (size_t)768 * 256 * 2;     // 384 KiB
  const size_t WP1_SZ = (size_t)256 * 256 * 2;    // 128 KiB
  if (ws_size < 5 * QB_SZ + W1_SZ + WP1_SZ) return;

  short* X1 = (short*)ws;
  short* Qbf = (short*)(ws + QB_SZ);
  short* Kbf = (short*)(ws + 2 * QB_SZ);
  short* Vbf = (short*)(ws + 3 * QB_SZ);
  short* AOh = (short*)(ws + 4 * QB_SZ);
  short* W1 = (short*)(ws + 5 * QB_SZ);
  short* WP1 = (short*)(ws + 5 * QB_SZ + W1_SZ);

  const int total_f4 = 4194304 + 49152 + 16384;
  cast_all<<<dim3((total_f4 + 255) / 256), 256, 0, stream>>>(x, Wqkv, Wproj,
                                                             X1, W1, WP1);
  gemm_bf_qkv<<<dim3(6 * 512), 256, 0, stream>>>(X1, W1, bqkv, Qbf, Kbf, Vbf);
  attn_v7<<<dim3(B_SZ * NB), 256, 0, stream>>>(Qbf, Kbf, Vbf, amask, efeat,
                                               Wgate, bgate, AOh);
  gemm_proj1<<<dim3(2 * 512), 256, 0, stream>>>(AOh, WP1, bproj, out);
}